// Round 6
// baseline (1062.445 us; speedup 1.0000x reference)
//
#include <hip/hip_runtime.h>

#define N_NODES 100000
#define N_EDGES 1600000
#define D 64
#define OVF_CAP 8192   // overflow edge list (backstop, expected unused)
#define N_TILES 1563   // (N_NODES + 63) / 64

// Binned segment-sum parameters.
#define NBUCK 782      // buckets of 128 nodes: 782*128 = 100096 >= N_NODES
#define NREG 8         // per-region streams (blockIdx&7) to localize lines
#define CAPB 448       // per region-bucket capacity: mean 256, sd 16 -> +12sd

// ws layout (bytes):
//   bcnt   @ 0         : NREG*NBUCK int   (25 KB)
//   bdata  @ 32768     : NREG*NBUCK*CAPB int (11.2 MB)
//   acc    @ 11243520  : N_NODES*D float  (25.6 MB)
//   ovfc   @ 36843520  : int
//   ovf    @ 36843536  : OVF_CAP int2
//   part   @ 36909312  : N_TILES*64 float (0.4 MB)
#define WS_BDATA_OFF 32768
#define WS_ACC_OFF   11243520
#define WS_OVFC_OFF  36843520
#define WS_OVF_OFF   36843536
#define WS_PART_OFF  36909312
#define WS_NEEDED    (WS_PART_OFF + N_TILES * 64 * 4)

// ---------------------------------------------------------------------------
// binA: bin edges by dst>>7 into 8 per-region sequential streams. Entry is
// 4B: (src<<7)|(dst&127). R5 fill's 96MB write-back came from 4B writes
// scattered over 25.6MB; bucket streams advance sequentially so write-back
// ~= payload (11MB). 8 edges/thread for atomic-latency overlap.
// ---------------------------------------------------------------------------
__global__ __launch_bounds__(256) void binA_kernel(
    const int* __restrict__ edge_src, const int* __restrict__ edge_dst,
    int* __restrict__ bcnt, int* __restrict__ bdata,
    int* __restrict__ ovf_cnt, int2* __restrict__ ovf) {
    const int t = blockIdx.x * 256 + threadIdx.x;
    const int r = blockIdx.x & (NREG - 1);
    if (t >= N_EDGES / 8) return;  // 200000 threads * 8 edges
    const int4* s4 = (const int4*)(edge_src + t * 8);
    const int4* d4 = (const int4*)(edge_dst + t * 8);
    int4 a0 = s4[0], a1 = s4[1], b0 = d4[0], b1 = d4[1];
    int ss[8] = {a0.x, a0.y, a0.z, a0.w, a1.x, a1.y, a1.z, a1.w};
    int dd[8] = {b0.x, b0.y, b0.z, b0.w, b1.x, b1.y, b1.z, b1.w};
    int pos[8], bk[8];
#pragma unroll
    for (int i = 0; i < 8; ++i) {
        bk[i] = dd[i] >> 7;
        pos[i] = atomicAdd(&bcnt[r * NBUCK + bk[i]], 1);
    }
#pragma unroll
    for (int i = 0; i < 8; ++i) {
        if (pos[i] < CAPB) {
            bdata[(r * NBUCK + bk[i]) * CAPB + pos[i]] = (ss[i] << 7) | (dd[i] & 127);
        } else {
            int j = atomicAdd(ovf_cnt, 1);
            if (j < OVF_CAP) ovf[j] = make_int2(ss[i], dd[i]);
        }
    }
}

// ---------------------------------------------------------------------------
// binB: one block per bucket (128 nodes). 32KB LDS accumulator. Per edge:
// one scalar entry load (wave-uniform index), one coalesced 256B emb-row
// load (emb is 25.6MB -> L3-resident), one ds_add_f32 per lane (addr%32 ==
// lane%32 -> 2 lanes/bank, free). Dense coalesced acc write. No global
// atomics anywhere.
// ---------------------------------------------------------------------------
__global__ __launch_bounds__(256) void binB_kernel(
    const float* __restrict__ emb, const int* __restrict__ bcnt,
    const int* __restrict__ bdata, float* __restrict__ acc) {
    __shared__ float lacc[128 * 64];  // 32 KB
    const int tid  = threadIdx.x;
    const int lane = tid & 63;
    const int wave = tid >> 6;
    const int b = blockIdx.x;

    float4* l4 = (float4*)lacc;
#pragma unroll
    for (int i = 0; i < 8; ++i) l4[tid + i * 256] = make_float4(0.f, 0.f, 0.f, 0.f);
    __syncthreads();

    for (int r = 0; r < NREG; ++r) {
        int n = bcnt[r * NBUCK + b];
        if (n > CAPB) n = CAPB;
        const int* __restrict__ base = bdata + (r * NBUCK + b) * CAPB;
        const int chunk = (n + 3) >> 2;
        const int i0 = wave * chunk;
        int i1 = i0 + chunk;
        if (i1 > n) i1 = n;
        int i = i0;
        for (; i + 4 <= i1; i += 4) {
            int e0 = base[i], e1 = base[i + 1], e2 = base[i + 2], e3 = base[i + 3];
            float v0 = emb[(e0 >> 7) * D + lane];
            float v1 = emb[(e1 >> 7) * D + lane];
            float v2 = emb[(e2 >> 7) * D + lane];
            float v3 = emb[(e3 >> 7) * D + lane];
            atomicAdd(&lacc[(e0 & 127) * D + lane], v0);
            atomicAdd(&lacc[(e1 & 127) * D + lane], v1);
            atomicAdd(&lacc[(e2 & 127) * D + lane], v2);
            atomicAdd(&lacc[(e3 & 127) * D + lane], v3);
        }
        for (; i < i1; ++i) {
            int e = base[i];
            atomicAdd(&lacc[(e & 127) * D + lane], emb[(e >> 7) * D + lane]);
        }
    }
    __syncthreads();

    // Write 128 rows (8192 floats = 2048 float4) densely, coalesced.
    const int node0 = b * 128;
    float4* acc4 = (float4*)acc;
#pragma unroll
    for (int i = 0; i < 8; ++i) {
        int idx = tid + i * 256;          // float4 index in tile
        int node = node0 + (idx >> 4);
        if (node < N_NODES) acc4[node * 16 + (idx & 15)] = l4[idx];
    }
}

// Overflow edges (normally zero): parallel, adds into acc AFTER binB.
__global__ __launch_bounds__(256) void ovf_kernel(
    const float* __restrict__ emb, const int* __restrict__ ovf_cnt,
    const int2* __restrict__ ovf, float* __restrict__ acc) {
    int n = *ovf_cnt;
    if (n > OVF_CAP) n = OVF_CAP;
    const int lane = threadIdx.x & 63;
    const int wv = (blockIdx.x * 256 + threadIdx.x) >> 6;
    const int nwaves = (gridDim.x * 256) >> 6;
    for (int i = wv; i < n; i += nwaves) {
        int2 e = ovf[i];
        unsafeAtomicAdd(&acc[e.y * D + lane], emb[e.x * D + lane]);
    }
}

// Fallback scatter (only if ws too small): one wave per edge, 64 f32 atomics.
__global__ __launch_bounds__(256) void scatter_kernel(
    const float* __restrict__ emb,
    const int* __restrict__ edge_src, const int* __restrict__ edge_dst,
    float* __restrict__ acc) {
    int gid = blockIdx.x * 256 + threadIdx.x;
    int e = gid >> 6;
    int c = gid & 63;
    unsafeAtomicAdd(&acc[edge_dst[e] * D + c], emb[edge_src[e] * D + c]);
}

// ---------------------------------------------------------------------------
// Final pass (unchanged from R4): per 64-node tile, z = feat@W1^T + nbr@W2^T
// with W1/W2 in LDS (uniform float4 broadcasts); relu(z+b); per-block
// partials via plain stores (atomic epilogue cost ~650us in R1/R3).
// ---------------------------------------------------------------------------
__global__ __launch_bounds__(256) void final_kernel(
    const float* __restrict__ feat, const float* __restrict__ acc,
    const float* __restrict__ W1, const float* __restrict__ b1,
    const float* __restrict__ W2, const float* __restrict__ b2,
    float* __restrict__ partials) {
    __shared__ float ft[64][65];   // [k][node]
    __shared__ float nt[64][65];
    __shared__ float w1s[64 * 64];
    __shared__ float w2s[64 * 64];

    const int tid  = threadIdx.x;
    const int lane = tid & 63;
    const int wave = tid >> 6;
    const int ob   = wave * 16;
    const int node0 = blockIdx.x * 64;

    {
        const float4* W1v = (const float4*)W1;
        const float4* W2v = (const float4*)W2;
        float4* w1v = (float4*)w1s;
        float4* w2v = (float4*)w2s;
#pragma unroll
        for (int i = 0; i < 4; ++i) {
            int idx = tid + i * 256;  // 0..1023
            w1v[idx] = W1v[idx];
            w2v[idx] = W2v[idx];
        }
    }

#pragma unroll 4
    for (int it = 0; it < 16; ++it) {
        const int r = wave + it * 4;
        const int node = node0 + r;
        float fv = 0.f, nv = 0.f;
        if (node < N_NODES) {
            fv = feat[node * D + lane];
            nv = acc[node * D + lane];
        }
        ft[lane][r] = fv;
        nt[lane][r] = nv;
    }
    __syncthreads();

    float z[16];
#pragma unroll
    for (int j = 0; j < 16; ++j) z[j] = 0.f;

    for (int k = 0; k < D; k += 4) {
        const float f0 = ft[k + 0][lane];
        const float f1 = ft[k + 1][lane];
        const float f2 = ft[k + 2][lane];
        const float f3 = ft[k + 3][lane];
        const float n0 = nt[k + 0][lane];
        const float n1 = nt[k + 1][lane];
        const float n2 = nt[k + 2][lane];
        const float n3 = nt[k + 3][lane];
#pragma unroll
        for (int j = 0; j < 16; ++j) {
            const float4 w1 = *(const float4*)&w1s[(ob + j) * 64 + k];
            const float4 w2 = *(const float4*)&w2s[(ob + j) * 64 + k];
            z[j] += f0 * w1.x + f1 * w1.y + f2 * w1.z + f3 * w1.w
                  + n0 * w2.x + n1 * w2.y + n2 * w2.z + n3 * w2.w;
        }
    }

    float sums[16];
    const int node = node0 + lane;
#pragma unroll
    for (int j = 0; j < 16; ++j) {
        float u = z[j] + b1[ob + j] + b2[ob + j];
        u = (u > 0.f) ? u : 0.f;
        sums[j] = (node < N_NODES) ? u : 0.f;
    }

#pragma unroll
    for (int j = 0; j < 16; ++j) {
        float v = sums[j];
        for (int off = 32; off > 0; off >>= 1) v += __shfl_down(v, off);
        if (lane == 0) partials[blockIdx.x * 64 + ob + j] = v;
    }
}

// Sum partials[N_TILES][64] -> out[64]. One block; coalesced; LDS combine.
__global__ __launch_bounds__(256) void reduce_kernel(
    const float* __restrict__ partials, float* __restrict__ out) {
    __shared__ float red[4][64];
    const int col = threadIdx.x & 63;
    const int seg = threadIdx.x >> 6;
    const int rows_per_seg = (N_TILES + 3) / 4;  // 391
    const int r0 = seg * rows_per_seg;
    int r1 = r0 + rows_per_seg;
    if (r1 > N_TILES) r1 = N_TILES;
    float s = 0.f;
    for (int r = r0; r < r1; ++r) s += partials[r * 64 + col];
    red[seg][col] = s;
    __syncthreads();
    if (seg == 0) {
        out[col] = red[0][col] + red[1][col] + red[2][col] + red[3][col];
    }
}

extern "C" void kernel_launch(void* const* d_in, const int* in_sizes, int n_in,
                              void* d_out, int out_size, void* d_ws, size_t ws_size,
                              hipStream_t stream) {
    const float* feat = (const float*)d_in[0];
    const float* emb  = (const float*)d_in[1];
    const float* W1   = (const float*)d_in[2];
    const float* b1   = (const float*)d_in[3];
    const float* W2   = (const float*)d_in[4];
    const float* b2   = (const float*)d_in[5];
    const int* edge_src = (const int*)d_in[6];
    const int* edge_dst = (const int*)d_in[7];
    float* out = (float*)d_out;
    char* ws = (char*)d_ws;

    if (ws_size >= (size_t)WS_NEEDED) {
        int*   bcnt     = (int*)ws;
        int*   bdata    = (int*)(ws + WS_BDATA_OFF);
        float* acc      = (float*)(ws + WS_ACC_OFF);
        int*   ovf_cnt  = (int*)(ws + WS_OVFC_OFF);
        int2*  ovf      = (int2*)(ws + WS_OVF_OFF);
        float* partials = (float*)(ws + WS_PART_OFF);

        hipMemsetAsync(bcnt, 0, NREG * NBUCK * sizeof(int), stream);
        hipMemsetAsync(ovf_cnt, 0, sizeof(int), stream);

        const int nthreads = N_EDGES / 8;  // 200000
        binA_kernel<<<(nthreads + 255) / 256, 256, 0, stream>>>(
            edge_src, edge_dst, bcnt, bdata, ovf_cnt, ovf);
        binB_kernel<<<NBUCK, 256, 0, stream>>>(emb, bcnt, bdata, acc);
        ovf_kernel<<<16, 256, 0, stream>>>(emb, ovf_cnt, ovf, acc);

        final_kernel<<<N_TILES, 256, 0, stream>>>(feat, acc, W1, b1, W2, b2,
                                                  partials);
        reduce_kernel<<<1, 256, 0, stream>>>(partials, out);
    } else {
        // Fallback: atomic scatter (correct but slow).
        float* acc = (float*)ws;
        hipMemsetAsync(acc, 0, (size_t)N_NODES * D * sizeof(float), stream);
        scatter_kernel<<<(N_EDGES * 64) / 256, 256, 0, stream>>>(emb, edge_src,
                                                                 edge_dst, acc);
        float* partials = (float*)(ws + (size_t)N_NODES * D * sizeof(float));
        final_kernel<<<N_TILES, 256, 0, stream>>>(feat, acc, W1, b1, W2, b2,
                                                  partials);
        reduce_kernel<<<1, 256, 0, stream>>>(partials, out);
    }
}

// Round 8
// 419.225 us; speedup vs baseline: 2.5343x; 2.5343x over previous
//
#include <hip/hip_runtime.h>

#define N_NODES 100000
#define N_EDGES 1600000
#define D 64
#define CAP 32         // slot cap per node; Poisson(16): P(deg>32)~1e-5/node, ovf backstops
#define OVF_CAP 8192   // overflow edge list (backstop)
#define N_TILES 1563   // (N_NODES + 63) / 64
#define NR 8           // region groups (dst>>14 -> 0..6; r==7 blocks idle)
#define SLICE_EDGES 2048
#define N_SLICES 782   // ceil(N_EDGES / SLICE_EDGES)

// Native clang vector type: __builtin_nontemporal_load accepts these
// (it rejects HIP_vector_type<int,4> — R7 compile failure).
typedef int vint4 __attribute__((ext_vector_type(4)));

// ws layout (bytes):
//   cnt    @ 0        : N_NODES int           (0.4 MB)
//   slots  @ 401408   : N_NODES*CAP int       (12.8 MB)
//   acc    @ 13201408 : N_NODES*D float       (25.6 MB)
//   ovfc   @ 38801408 : int
//   ovf    @ 38801424 : OVF_CAP int2
//   part   @ 38867200 : N_TILES*64 float      (0.4 MB)
#define WS_SLOTS_OFF 401408
#define WS_ACC_OFF   13201408
#define WS_OVFC_OFF  38801408
#define WS_OVF_OFF   38801424
#define WS_PART_OFF  38867200
#define WS_NEEDED    (WS_PART_OFF + N_TILES * 64 * 4)

// ---------------------------------------------------------------------------
// Region-partitioned CSR fill. R5's flat fill wrote 4B entries scattered over
// 25.6MB -> ~96MB of dirty-line write-back (measured). Here block r=bIdx&7
// scans a 2048-edge slice and keeps only edges with dst>>14 == r; under
// stride-8 XCD round-robin dispatch all writers of region r share one XCD,
// and the region's slot array (16384 nodes * 32 * 4B = 2MB) stays resident
// in that XCD's 4MB L2 -> write-back ~= payload. Edge scan reads are
// NONTEMPORAL so 12.8MB/region of streaming doesn't evict dirty slot lines.
// Cost: 8x sequential re-read of the edge list (~102MB, ~16us at stream BW).
// ---------------------------------------------------------------------------
__global__ __launch_bounds__(256) void fill_kernel(
    const int* __restrict__ edge_src, const int* __restrict__ edge_dst,
    int* __restrict__ cnt, int* __restrict__ slots,
    int* __restrict__ ovf_cnt, int2* __restrict__ ovf) {
    const int r = blockIdx.x & (NR - 1);
    if (r == 7) return;                    // region 7 is empty (dst < 114688)
    const int slice = blockIdx.x >> 3;
    const int base_e = slice * SLICE_EDGES + threadIdx.x * 8;
    if (base_e >= N_EDGES) return;         // ragged last slice (multiple of 8)
    const vint4* s4 = (const vint4*)(edge_src + base_e);
    const vint4* d4 = (const vint4*)(edge_dst + base_e);
    vint4 a0 = __builtin_nontemporal_load(s4);
    vint4 a1 = __builtin_nontemporal_load(s4 + 1);
    vint4 b0 = __builtin_nontemporal_load(d4);
    vint4 b1 = __builtin_nontemporal_load(d4 + 1);
    int ss[8] = {a0.x, a0.y, a0.z, a0.w, a1.x, a1.y, a1.z, a1.w};
    int dd[8] = {b0.x, b0.y, b0.z, b0.w, b1.x, b1.y, b1.z, b1.w};
#pragma unroll
    for (int i = 0; i < 8; ++i) {
        if ((dd[i] >> 14) == r) {
            int pos = atomicAdd(&cnt[dd[i]], 1);
            if (pos < CAP) {
                slots[dd[i] * CAP + pos] = ss[i];
            } else {
                int j = atomicAdd(ovf_cnt, 1);
                if (j < OVF_CAP) ovf[j] = make_int2(ss[i], dd[i]);
            }
        }
    }
}

// ---------------------------------------------------------------------------
// Atomic-free gather (R5-proven structure, CAP=32). One wave per node.
// Lane = (q, c4): q = lane>>4 picks slot e+q, c4 = lane&15 picks the float4
// column group. One VMEM instr fetches FOUR emb rows; butterfly over q
// combines; q==0 lanes store the full 256B acc row.
// ---------------------------------------------------------------------------
__global__ __launch_bounds__(256) void gather_kernel(
    const float* __restrict__ emb, const int* __restrict__ cnt,
    const int* __restrict__ slots, float* __restrict__ acc) {
    const int lane = threadIdx.x & 63;
    const int wave = threadIdx.x >> 6;
    const int v = blockIdx.x * 4 + wave;  // grid = N_NODES/4 exactly
    const int q  = lane >> 4;
    const int c4 = lane & 15;
    int deg = cnt[v];
    if (deg > CAP) deg = CAP;
    const int si = slots[v * CAP + (lane & (CAP - 1))];  // coalesced 128B row
    const float4* emb4 = (const float4*)emb;

    float4 sum = make_float4(0.f, 0.f, 0.f, 0.f);
    for (int e = 0; e < deg; e += 4) {
        const int idx = e + q;
        const int s = __shfl(si, idx & (CAP - 1));
        if (idx < deg) {
            float4 a = emb4[s * 16 + c4];
            sum.x += a.x; sum.y += a.y; sum.z += a.z; sum.w += a.w;
        }
    }
#pragma unroll
    for (int off = 16; off < 64; off <<= 1) {
        sum.x += __shfl_xor(sum.x, off);
        sum.y += __shfl_xor(sum.y, off);
        sum.z += __shfl_xor(sum.z, off);
        sum.w += __shfl_xor(sum.w, off);
    }
    if (q == 0) {
        ((float4*)acc)[v * 16 + c4] = sum;
    }
}

// Overflow edges (a handful at CAP=32): parallel, adds into acc AFTER gather.
__global__ __launch_bounds__(256) void ovf_kernel(
    const float* __restrict__ emb, const int* __restrict__ ovf_cnt,
    const int2* __restrict__ ovf, float* __restrict__ acc) {
    int n = *ovf_cnt;
    if (n > OVF_CAP) n = OVF_CAP;
    const int lane = threadIdx.x & 63;
    const int wv = (blockIdx.x * 256 + threadIdx.x) >> 6;
    const int nwaves = (gridDim.x * 256) >> 6;
    for (int i = wv; i < n; i += nwaves) {
        int2 e = ovf[i];
        unsafeAtomicAdd(&acc[e.y * D + lane], emb[e.x * D + lane]);
    }
}

// Fallback scatter (only if ws too small): one wave per edge, 64 f32 atomics.
__global__ __launch_bounds__(256) void scatter_kernel(
    const float* __restrict__ emb,
    const int* __restrict__ edge_src, const int* __restrict__ edge_dst,
    float* __restrict__ acc) {
    int gid = blockIdx.x * 256 + threadIdx.x;
    int e = gid >> 6;
    int c = gid & 63;
    unsafeAtomicAdd(&acc[edge_dst[e] * D + c], emb[edge_src[e] * D + c]);
}

// ---------------------------------------------------------------------------
// Final pass (R4-proven): per 64-node tile, z = feat@W1^T + nbr@W2^T with
// W1/W2 in LDS (uniform float4 broadcasts); relu(z+b); per-block partials
// via plain stores (the atomic epilogue into out[64] cost ~650us in R1/R3).
// ---------------------------------------------------------------------------
__global__ __launch_bounds__(256) void final_kernel(
    const float* __restrict__ feat, const float* __restrict__ acc,
    const float* __restrict__ W1, const float* __restrict__ b1,
    const float* __restrict__ W2, const float* __restrict__ b2,
    float* __restrict__ partials) {
    __shared__ float ft[64][65];   // [k][node]
    __shared__ float nt[64][65];
    __shared__ float w1s[64 * 64];
    __shared__ float w2s[64 * 64];

    const int tid  = threadIdx.x;
    const int lane = tid & 63;
    const int wave = tid >> 6;
    const int ob   = wave * 16;
    const int node0 = blockIdx.x * 64;

    {
        const float4* W1v = (const float4*)W1;
        const float4* W2v = (const float4*)W2;
        float4* w1v = (float4*)w1s;
        float4* w2v = (float4*)w2s;
#pragma unroll
        for (int i = 0; i < 4; ++i) {
            int idx = tid + i * 256;  // 0..1023
            w1v[idx] = W1v[idx];
            w2v[idx] = W2v[idx];
        }
    }

#pragma unroll 4
    for (int it = 0; it < 16; ++it) {
        const int r = wave + it * 4;
        const int node = node0 + r;
        float fv = 0.f, nv = 0.f;
        if (node < N_NODES) {
            fv = feat[node * D + lane];
            nv = acc[node * D + lane];
        }
        ft[lane][r] = fv;
        nt[lane][r] = nv;
    }
    __syncthreads();

    float z[16];
#pragma unroll
    for (int j = 0; j < 16; ++j) z[j] = 0.f;

    for (int k = 0; k < D; k += 4) {
        const float f0 = ft[k + 0][lane];
        const float f1 = ft[k + 1][lane];
        const float f2 = ft[k + 2][lane];
        const float f3 = ft[k + 3][lane];
        const float n0 = nt[k + 0][lane];
        const float n1 = nt[k + 1][lane];
        const float n2 = nt[k + 2][lane];
        const float n3 = nt[k + 3][lane];
#pragma unroll
        for (int j = 0; j < 16; ++j) {
            const float4 w1 = *(const float4*)&w1s[(ob + j) * 64 + k];
            const float4 w2 = *(const float4*)&w2s[(ob + j) * 64 + k];
            z[j] += f0 * w1.x + f1 * w1.y + f2 * w1.z + f3 * w1.w
                  + n0 * w2.x + n1 * w2.y + n2 * w2.z + n3 * w2.w;
        }
    }

    float sums[16];
    const int node = node0 + lane;
#pragma unroll
    for (int j = 0; j < 16; ++j) {
        float u = z[j] + b1[ob + j] + b2[ob + j];
        u = (u > 0.f) ? u : 0.f;
        sums[j] = (node < N_NODES) ? u : 0.f;
    }

#pragma unroll
    for (int j = 0; j < 16; ++j) {
        float v = sums[j];
        for (int off = 32; off > 0; off >>= 1) v += __shfl_down(v, off);
        if (lane == 0) partials[blockIdx.x * 64 + ob + j] = v;
    }
}

// Sum partials[N_TILES][64] -> out[64]. One block; coalesced; LDS combine.
__global__ __launch_bounds__(256) void reduce_kernel(
    const float* __restrict__ partials, float* __restrict__ out) {
    __shared__ float red[4][64];
    const int col = threadIdx.x & 63;
    const int seg = threadIdx.x >> 6;
    const int rows_per_seg = (N_TILES + 3) / 4;  // 391
    const int r0 = seg * rows_per_seg;
    int r1 = r0 + rows_per_seg;
    if (r1 > N_TILES) r1 = N_TILES;
    float s = 0.f;
    for (int r = r0; r < r1; ++r) s += partials[r * 64 + col];
    red[seg][col] = s;
    __syncthreads();
    if (seg == 0) {
        out[col] = red[0][col] + red[1][col] + red[2][col] + red[3][col];
    }
}

extern "C" void kernel_launch(void* const* d_in, const int* in_sizes, int n_in,
                              void* d_out, int out_size, void* d_ws, size_t ws_size,
                              hipStream_t stream) {
    const float* feat = (const float*)d_in[0];
    const float* emb  = (const float*)d_in[1];
    const float* W1   = (const float*)d_in[2];
    const float* b1   = (const float*)d_in[3];
    const float* W2   = (const float*)d_in[4];
    const float* b2   = (const float*)d_in[5];
    const int* edge_src = (const int*)d_in[6];
    const int* edge_dst = (const int*)d_in[7];
    float* out = (float*)d_out;
    char* ws = (char*)d_ws;

    if (ws_size >= (size_t)WS_NEEDED) {
        int*   cnt      = (int*)ws;
        int*   slots    = (int*)(ws + WS_SLOTS_OFF);
        float* acc      = (float*)(ws + WS_ACC_OFF);
        int*   ovf_cnt  = (int*)(ws + WS_OVFC_OFF);
        int2*  ovf      = (int2*)(ws + WS_OVF_OFF);
        float* partials = (float*)(ws + WS_PART_OFF);

        (void)hipMemsetAsync(cnt, 0, N_NODES * sizeof(int), stream);
        (void)hipMemsetAsync(ovf_cnt, 0, sizeof(int), stream);

        fill_kernel<<<NR * N_SLICES, 256, 0, stream>>>(edge_src, edge_dst,
                                                       cnt, slots, ovf_cnt, ovf);
        gather_kernel<<<N_NODES / 4, 256, 0, stream>>>(emb, cnt, slots, acc);
        ovf_kernel<<<16, 256, 0, stream>>>(emb, ovf_cnt, ovf, acc);

        final_kernel<<<N_TILES, 256, 0, stream>>>(feat, acc, W1, b1, W2, b2,
                                                  partials);
        reduce_kernel<<<1, 256, 0, stream>>>(partials, out);
    } else {
        // Fallback: atomic scatter (correct but slow).
        float* acc = (float*)ws;
        (void)hipMemsetAsync(acc, 0, (size_t)N_NODES * D * sizeof(float), stream);
        scatter_kernel<<<(N_EDGES * 64) / 256, 256, 0, stream>>>(emb, edge_src,
                                                                 edge_dst, acc);
        float* partials = (float*)(ws + (size_t)N_NODES * D * sizeof(float));
        final_kernel<<<N_TILES, 256, 0, stream>>>(feat, acc, W1, b1, W2, b2,
                                                  partials);
        reduce_kernel<<<1, 256, 0, stream>>>(partials, out);
    }
}

// Round 9
// 318.183 us; speedup vs baseline: 3.3391x; 1.3176x over previous
//
#include <hip/hip_runtime.h>

#define N_NODES 100000
#define N_EDGES 1600000
#define D 64
#define CAP 32         // slot cap per node; Poisson(16): P(deg>32)~1e-5/node, ovf backstops
#define OVF_CAP 8192   // overflow edge list (backstop)
#define N_TILES 1563   // (N_NODES + 63) / 64
#define NR 8           // region groups (dst>>14 -> 0..6; r==7 blocks idle)
#define SLICE_EDGES 2048
#define N_SLICES 782   // ceil(N_EDGES / SLICE_EDGES)
#define R1_BLOCKS 64   // stage-1 reduce blocks
#define R1_ROWS 25     // ceil(N_TILES / R1_BLOCKS)

// Native clang vector type: __builtin_nontemporal_load accepts these
// (it rejects HIP_vector_type<int,4> — R7 compile failure).
typedef int vint4 __attribute__((ext_vector_type(4)));

// ws layout (bytes):
//   cnt    @ 0        : N_NODES int           (0.4 MB)
//   slots  @ 401408   : N_NODES*CAP int       (12.8 MB)
//   acc    @ 13201408 : N_NODES*D float       (25.6 MB)
//   ovfc   @ 38801408 : int
//   ovf    @ 38801424 : OVF_CAP int2
//   part   @ 38867200 : N_TILES*64 float      (0.4 MB)
//   part2  @ 39267328 : R1_BLOCKS*64 float    (16 KB)
#define WS_SLOTS_OFF 401408
#define WS_ACC_OFF   13201408
#define WS_OVFC_OFF  38801408
#define WS_OVF_OFF   38801424
#define WS_PART_OFF  38867200
#define WS_PART2_OFF 39267328
#define WS_NEEDED    (WS_PART2_OFF + R1_BLOCKS * 64 * 4)

// ---------------------------------------------------------------------------
// Region-partitioned CSR fill (R8-proven: fill left the top-5). Block
// r=bIdx&7 scans a 2048-edge slice keeping only dst>>14 == r; region's slot
// array (2MB) stays L2-resident -> write-back ~= payload, not the 96MB of
// R5's scattered fill. Edge reads nontemporal.
// ---------------------------------------------------------------------------
__global__ __launch_bounds__(256) void fill_kernel(
    const int* __restrict__ edge_src, const int* __restrict__ edge_dst,
    int* __restrict__ cnt, int* __restrict__ slots,
    int* __restrict__ ovf_cnt, int2* __restrict__ ovf) {
    const int r = blockIdx.x & (NR - 1);
    if (r == 7) return;                    // region 7 is empty (dst < 114688)
    const int slice = blockIdx.x >> 3;
    const int base_e = slice * SLICE_EDGES + threadIdx.x * 8;
    if (base_e >= N_EDGES) return;         // ragged last slice (multiple of 8)
    const vint4* s4 = (const vint4*)(edge_src + base_e);
    const vint4* d4 = (const vint4*)(edge_dst + base_e);
    vint4 a0 = __builtin_nontemporal_load(s4);
    vint4 a1 = __builtin_nontemporal_load(s4 + 1);
    vint4 b0 = __builtin_nontemporal_load(d4);
    vint4 b1 = __builtin_nontemporal_load(d4 + 1);
    int ss[8] = {a0.x, a0.y, a0.z, a0.w, a1.x, a1.y, a1.z, a1.w};
    int dd[8] = {b0.x, b0.y, b0.z, b0.w, b1.x, b1.y, b1.z, b1.w};
#pragma unroll
    for (int i = 0; i < 8; ++i) {
        if ((dd[i] >> 14) == r) {
            int pos = atomicAdd(&cnt[dd[i]], 1);
            if (pos < CAP) {
                slots[dd[i] * CAP + pos] = ss[i];
            } else {
                int j = atomicAdd(ovf_cnt, 1);
                if (j < OVF_CAP) ovf[j] = make_int2(ss[i], dd[i]);
            }
        }
    }
}

// ---------------------------------------------------------------------------
// Atomic-free gather (R5-proven structure, CAP=32). One wave per node.
// Lane = (q, c4): q = lane>>4 picks slot e+q, c4 = lane&15 picks the float4
// column group. One VMEM instr fetches FOUR emb rows; butterfly over q
// combines; q==0 lanes store the full 256B acc row.
// ---------------------------------------------------------------------------
__global__ __launch_bounds__(256) void gather_kernel(
    const float* __restrict__ emb, const int* __restrict__ cnt,
    const int* __restrict__ slots, float* __restrict__ acc) {
    const int lane = threadIdx.x & 63;
    const int wave = threadIdx.x >> 6;
    const int v = blockIdx.x * 4 + wave;  // grid = N_NODES/4 exactly
    const int q  = lane >> 4;
    const int c4 = lane & 15;
    int deg = cnt[v];
    if (deg > CAP) deg = CAP;
    const int si = slots[v * CAP + (lane & (CAP - 1))];  // coalesced 128B row
    const float4* emb4 = (const float4*)emb;

    float4 sum = make_float4(0.f, 0.f, 0.f, 0.f);
    for (int e = 0; e < deg; e += 4) {
        const int idx = e + q;
        const int s = __shfl(si, idx & (CAP - 1));
        if (idx < deg) {
            float4 a = emb4[s * 16 + c4];
            sum.x += a.x; sum.y += a.y; sum.z += a.z; sum.w += a.w;
        }
    }
#pragma unroll
    for (int off = 16; off < 64; off <<= 1) {
        sum.x += __shfl_xor(sum.x, off);
        sum.y += __shfl_xor(sum.y, off);
        sum.z += __shfl_xor(sum.z, off);
        sum.w += __shfl_xor(sum.w, off);
    }
    if (q == 0) {
        ((float4*)acc)[v * 16 + c4] = sum;
    }
}

// Overflow edges (a handful at CAP=32): parallel, adds into acc AFTER gather.
__global__ __launch_bounds__(256) void ovf_kernel(
    const float* __restrict__ emb, const int* __restrict__ ovf_cnt,
    const int2* __restrict__ ovf, float* __restrict__ acc) {
    int n = *ovf_cnt;
    if (n > OVF_CAP) n = OVF_CAP;
    const int lane = threadIdx.x & 63;
    const int wv = (blockIdx.x * 256 + threadIdx.x) >> 6;
    const int nwaves = (gridDim.x * 256) >> 6;
    for (int i = wv; i < n; i += nwaves) {
        int2 e = ovf[i];
        unsafeAtomicAdd(&acc[e.y * D + lane], emb[e.x * D + lane]);
    }
}

// Fallback scatter (only if ws too small): one wave per edge, 64 f32 atomics.
__global__ __launch_bounds__(256) void scatter_kernel(
    const float* __restrict__ emb,
    const int* __restrict__ edge_src, const int* __restrict__ edge_dst,
    float* __restrict__ acc) {
    int gid = blockIdx.x * 256 + threadIdx.x;
    int e = gid >> 6;
    int c = gid & 63;
    unsafeAtomicAdd(&acc[edge_dst[e] * D + c], emb[edge_src[e] * D + c]);
}

// ---------------------------------------------------------------------------
// Final pass (R4-proven): per 64-node tile, z = feat@W1^T + nbr@W2^T with
// W1/W2 in LDS (uniform float4 broadcasts); relu(z+b); per-block partials
// via plain stores (the atomic epilogue into out[64] cost ~650us in R1/R3).
// ---------------------------------------------------------------------------
__global__ __launch_bounds__(256) void final_kernel(
    const float* __restrict__ feat, const float* __restrict__ acc,
    const float* __restrict__ W1, const float* __restrict__ b1,
    const float* __restrict__ W2, const float* __restrict__ b2,
    float* __restrict__ partials) {
    __shared__ float ft[64][65];   // [k][node]
    __shared__ float nt[64][65];
    __shared__ float w1s[64 * 64];
    __shared__ float w2s[64 * 64];

    const int tid  = threadIdx.x;
    const int lane = tid & 63;
    const int wave = tid >> 6;
    const int ob   = wave * 16;
    const int node0 = blockIdx.x * 64;

    {
        const float4* W1v = (const float4*)W1;
        const float4* W2v = (const float4*)W2;
        float4* w1v = (float4*)w1s;
        float4* w2v = (float4*)w2s;
#pragma unroll
        for (int i = 0; i < 4; ++i) {
            int idx = tid + i * 256;  // 0..1023
            w1v[idx] = W1v[idx];
            w2v[idx] = W2v[idx];
        }
    }

#pragma unroll 4
    for (int it = 0; it < 16; ++it) {
        const int r = wave + it * 4;
        const int node = node0 + r;
        float fv = 0.f, nv = 0.f;
        if (node < N_NODES) {
            fv = feat[node * D + lane];
            nv = acc[node * D + lane];
        }
        ft[lane][r] = fv;
        nt[lane][r] = nv;
    }
    __syncthreads();

    float z[16];
#pragma unroll
    for (int j = 0; j < 16; ++j) z[j] = 0.f;

    for (int k = 0; k < D; k += 4) {
        const float f0 = ft[k + 0][lane];
        const float f1 = ft[k + 1][lane];
        const float f2 = ft[k + 2][lane];
        const float f3 = ft[k + 3][lane];
        const float n0 = nt[k + 0][lane];
        const float n1 = nt[k + 1][lane];
        const float n2 = nt[k + 2][lane];
        const float n3 = nt[k + 3][lane];
#pragma unroll
        for (int j = 0; j < 16; ++j) {
            const float4 w1 = *(const float4*)&w1s[(ob + j) * 64 + k];
            const float4 w2 = *(const float4*)&w2s[(ob + j) * 64 + k];
            z[j] += f0 * w1.x + f1 * w1.y + f2 * w1.z + f3 * w1.w
                  + n0 * w2.x + n1 * w2.y + n2 * w2.z + n3 * w2.w;
        }
    }

    float sums[16];
    const int node = node0 + lane;
#pragma unroll
    for (int j = 0; j < 16; ++j) {
        float u = z[j] + b1[ob + j] + b2[ob + j];
        u = (u > 0.f) ? u : 0.f;
        sums[j] = (node < N_NODES) ? u : 0.f;
    }

#pragma unroll
    for (int j = 0; j < 16; ++j) {
        float v = sums[j];
        for (int off = 32; off > 0; off >>= 1) v += __shfl_down(v, off);
        if (lane == 0) partials[blockIdx.x * 64 + ob + j] = v;
    }
}

// ---------------------------------------------------------------------------
// Two-stage partials reduction. R8's single-block reduce was 110us (one CU,
// ~391 L2-miss latencies deep, 1.8 GB/s): classic tiny-launch latency bind.
// Stage 1: 64 blocks x ~25 rows each -> part2[64][64]. Stage 2: 1 block
// sums 64 rows (~16 loads/thread). Both coalesced plain stores.
// ---------------------------------------------------------------------------
__global__ __launch_bounds__(256) void reduce1_kernel(
    const float* __restrict__ partials, float* __restrict__ part2) {
    __shared__ float red[4][64];
    const int col = threadIdx.x & 63;
    const int seg = threadIdx.x >> 6;
    const int r0 = blockIdx.x * R1_ROWS;
    int r1 = r0 + R1_ROWS;
    if (r1 > N_TILES) r1 = N_TILES;
    float s = 0.f;
    for (int r = r0 + seg; r < r1; r += 4) s += partials[r * 64 + col];
    red[seg][col] = s;
    __syncthreads();
    if (seg == 0) {
        part2[blockIdx.x * 64 + col] =
            red[0][col] + red[1][col] + red[2][col] + red[3][col];
    }
}

__global__ __launch_bounds__(256) void reduce2_kernel(
    const float* __restrict__ part2, float* __restrict__ out) {
    __shared__ float red[4][64];
    const int col = threadIdx.x & 63;
    const int seg = threadIdx.x >> 6;
    float s = 0.f;
    for (int r = seg; r < R1_BLOCKS; r += 4) s += part2[r * 64 + col];
    red[seg][col] = s;
    __syncthreads();
    if (seg == 0) {
        out[col] = red[0][col] + red[1][col] + red[2][col] + red[3][col];
    }
}

extern "C" void kernel_launch(void* const* d_in, const int* in_sizes, int n_in,
                              void* d_out, int out_size, void* d_ws, size_t ws_size,
                              hipStream_t stream) {
    const float* feat = (const float*)d_in[0];
    const float* emb  = (const float*)d_in[1];
    const float* W1   = (const float*)d_in[2];
    const float* b1   = (const float*)d_in[3];
    const float* W2   = (const float*)d_in[4];
    const float* b2   = (const float*)d_in[5];
    const int* edge_src = (const int*)d_in[6];
    const int* edge_dst = (const int*)d_in[7];
    float* out = (float*)d_out;
    char* ws = (char*)d_ws;

    if (ws_size >= (size_t)WS_NEEDED) {
        int*   cnt      = (int*)ws;
        int*   slots    = (int*)(ws + WS_SLOTS_OFF);
        float* acc      = (float*)(ws + WS_ACC_OFF);
        int*   ovf_cnt  = (int*)(ws + WS_OVFC_OFF);
        int2*  ovf      = (int2*)(ws + WS_OVF_OFF);
        float* partials = (float*)(ws + WS_PART_OFF);
        float* part2    = (float*)(ws + WS_PART2_OFF);

        (void)hipMemsetAsync(cnt, 0, N_NODES * sizeof(int), stream);
        (void)hipMemsetAsync(ovf_cnt, 0, sizeof(int), stream);

        fill_kernel<<<NR * N_SLICES, 256, 0, stream>>>(edge_src, edge_dst,
                                                       cnt, slots, ovf_cnt, ovf);
        gather_kernel<<<N_NODES / 4, 256, 0, stream>>>(emb, cnt, slots, acc);
        ovf_kernel<<<16, 256, 0, stream>>>(emb, ovf_cnt, ovf, acc);

        final_kernel<<<N_TILES, 256, 0, stream>>>(feat, acc, W1, b1, W2, b2,
                                                  partials);
        reduce1_kernel<<<R1_BLOCKS, 256, 0, stream>>>(partials, part2);
        reduce2_kernel<<<1, 256, 0, stream>>>(part2, out);
    } else {
        // Fallback: atomic scatter (correct but slow).
        float* acc = (float*)ws;
        (void)hipMemsetAsync(acc, 0, (size_t)N_NODES * D * sizeof(float), stream);
        scatter_kernel<<<(N_EDGES * 64) / 256, 256, 0, stream>>>(emb, edge_src,
                                                                 edge_dst, acc);
        float* partials = (float*)(ws + (size_t)N_NODES * D * sizeof(float));
        float* part2    = partials + (size_t)N_TILES * 64;
        final_kernel<<<N_TILES, 256, 0, stream>>>(feat, acc, W1, b1, W2, b2,
                                                  partials);
        reduce1_kernel<<<R1_BLOCKS, 256, 0, stream>>>(partials, part2);
        reduce2_kernel<<<1, 256, 0, stream>>>(part2, out);
    }
}

// Round 12
// 253.282 us; speedup vs baseline: 4.1947x; 1.2562x over previous
//
#include <hip/hip_runtime.h>

#define N_NODES 100000
#define N_EDGES 1600000
#define D 64
#define CAP 32         // slot cap per node; Poisson(16): P(deg>32)~1e-5/node, ovf backstops
#define OVF_CAP 8192   // overflow edge list (backstop)
#define N_TILES 1563   // (N_NODES + 63) / 64
#define NR 8           // region groups (dst>>14 -> 0..6; r==7 blocks idle)
#define SLICE_EDGES 2048
#define N_SLICES 782   // ceil(N_EDGES / SLICE_EDGES)
#define R1_BLOCKS 64   // stage-1 reduce blocks
#define R1_ROWS 25     // ceil(N_TILES / R1_BLOCKS)
#define ASTRIDE 136    // LDS row stride in bf16 elems (128 + 8 pad, 16B-aligned)

typedef int    vint4  __attribute__((ext_vector_type(4)));
typedef short  s16x4  __attribute__((ext_vector_type(4)));
typedef short  s16x8  __attribute__((ext_vector_type(8)));
typedef float  f32x4  __attribute__((ext_vector_type(4)));
typedef __bf16 bf16x8 __attribute__((ext_vector_type(8)));  // MFMA operand type

// f32 -> bf16 (RNE). Inputs are finite; NaN path not needed.
__device__ inline short f2bf(float f) {
    unsigned u = __builtin_bit_cast(unsigned, f);
    u += 0x7fffu + ((u >> 16) & 1u);
    return (short)(u >> 16);
}
__device__ inline s16x4 f2bf4(float4 v) {
    s16x4 r; r.x = f2bf(v.x); r.y = f2bf(v.y); r.z = f2bf(v.z); r.w = f2bf(v.w);
    return r;
}

// ws layout (bytes):
//   cnt    @ 0        : N_NODES int           (0.4 MB)
//   slots  @ 401408   : N_NODES*CAP int       (12.8 MB)
//   acc    @ 13201408 : N_NODES*D float       (25.6 MB)
//   ovfc   @ 38801408 : int
//   ovf    @ 38801424 : OVF_CAP int2
//   part   @ 38867200 : N_TILES*64 float      (0.4 MB)
//   part2  @ 39267328 : R1_BLOCKS*64 float    (16 KB)
#define WS_SLOTS_OFF 401408
#define WS_ACC_OFF   13201408
#define WS_OVFC_OFF  38801408
#define WS_OVF_OFF   38801424
#define WS_PART_OFF  38867200
#define WS_PART2_OFF 39267328
#define WS_NEEDED    (WS_PART2_OFF + R1_BLOCKS * 64 * 4)

// ---------------------------------------------------------------------------
// Region-partitioned CSR fill (R8-proven). Block r=bIdx&7 scans a 2048-edge
// slice keeping only dst>>14 == r; region's 2MB slot array stays L2-resident
// -> write-back ~= payload (vs 96MB for the R5 scattered fill). Nontemporal
// edge reads.
// ---------------------------------------------------------------------------
__global__ __launch_bounds__(256) void fill_kernel(
    const int* __restrict__ edge_src, const int* __restrict__ edge_dst,
    int* __restrict__ cnt, int* __restrict__ slots,
    int* __restrict__ ovf_cnt, int2* __restrict__ ovf) {
    const int r = blockIdx.x & (NR - 1);
    if (r == 7) return;
    const int slice = blockIdx.x >> 3;
    const int base_e = slice * SLICE_EDGES + threadIdx.x * 8;
    if (base_e >= N_EDGES) return;
    const vint4* s4 = (const vint4*)(edge_src + base_e);
    const vint4* d4 = (const vint4*)(edge_dst + base_e);
    vint4 a0 = __builtin_nontemporal_load(s4);
    vint4 a1 = __builtin_nontemporal_load(s4 + 1);
    vint4 b0 = __builtin_nontemporal_load(d4);
    vint4 b1 = __builtin_nontemporal_load(d4 + 1);
    int ss[8] = {a0.x, a0.y, a0.z, a0.w, a1.x, a1.y, a1.z, a1.w};
    int dd[8] = {b0.x, b0.y, b0.z, b0.w, b1.x, b1.y, b1.z, b1.w};
#pragma unroll
    for (int i = 0; i < 8; ++i) {
        if ((dd[i] >> 14) == r) {
            int pos = atomicAdd(&cnt[dd[i]], 1);
            if (pos < CAP) {
                slots[dd[i] * CAP + pos] = ss[i];
            } else {
                int j = atomicAdd(ovf_cnt, 1);
                if (j < OVF_CAP) ovf[j] = make_int2(ss[i], dd[i]);
            }
        }
    }
}

// ---------------------------------------------------------------------------
// Atomic-free gather (R5-proven, CAP=32). One wave per node; q=lane>>4 picks
// slot e+q, c4=lane&15 picks float4 column; butterfly over q; q==0 stores.
// ---------------------------------------------------------------------------
__global__ __launch_bounds__(256) void gather_kernel(
    const float* __restrict__ emb, const int* __restrict__ cnt,
    const int* __restrict__ slots, float* __restrict__ acc) {
    const int lane = threadIdx.x & 63;
    const int wave = threadIdx.x >> 6;
    const int v = blockIdx.x * 4 + wave;
    const int q  = lane >> 4;
    const int c4 = lane & 15;
    int deg = cnt[v];
    if (deg > CAP) deg = CAP;
    const int si = slots[v * CAP + (lane & (CAP - 1))];
    const float4* emb4 = (const float4*)emb;

    float4 sum = make_float4(0.f, 0.f, 0.f, 0.f);
    for (int e = 0; e < deg; e += 4) {
        const int idx = e + q;
        const int s = __shfl(si, idx & (CAP - 1));
        if (idx < deg) {
            float4 a = emb4[s * 16 + c4];
            sum.x += a.x; sum.y += a.y; sum.z += a.z; sum.w += a.w;
        }
    }
#pragma unroll
    for (int off = 16; off < 64; off <<= 1) {
        sum.x += __shfl_xor(sum.x, off);
        sum.y += __shfl_xor(sum.y, off);
        sum.z += __shfl_xor(sum.z, off);
        sum.w += __shfl_xor(sum.w, off);
    }
    if (q == 0) {
        ((float4*)acc)[v * 16 + c4] = sum;
    }
}

// Overflow edges (a handful at CAP=32): parallel, adds into acc AFTER gather.
__global__ __launch_bounds__(256) void ovf_kernel(
    const float* __restrict__ emb, const int* __restrict__ ovf_cnt,
    const int2* __restrict__ ovf, float* __restrict__ acc) {
    int n = *ovf_cnt;
    if (n > OVF_CAP) n = OVF_CAP;
    const int lane = threadIdx.x & 63;
    const int wv = (blockIdx.x * 256 + threadIdx.x) >> 6;
    const int nwaves = (gridDim.x * 256) >> 6;
    for (int i = wv; i < n; i += nwaves) {
        int2 e = ovf[i];
        unsafeAtomicAdd(&acc[e.y * D + lane], emb[e.x * D + lane]);
    }
}

// Fallback scatter (only if ws too small).
__global__ __launch_bounds__(256) void scatter_kernel(
    const float* __restrict__ emb,
    const int* __restrict__ edge_src, const int* __restrict__ edge_dst,
    float* __restrict__ acc) {
    int gid = blockIdx.x * 256 + threadIdx.x;
    int e = gid >> 6;
    int c = gid & 63;
    unsafeAtomicAdd(&acc[edge_dst[e] * D + c], emb[edge_src[e] * D + c]);
}

// ---------------------------------------------------------------------------
// Final pass, MFMA. z = [feat|nbr] @ [W1|W2]^T, K=128, mfma_f32_16x16x32_bf16
// (4 k-steps). R9's f32 version was LDS-issue-bound: 512 wave-uniform
// ds_read_b128 of W per thread > FMA cost. Here W fragments are hoisted into
// 64 VGPRs once per block; per 16-node strip a wave issues 4 A-frag reads +
// 16 MFMAs. Fragment layouts (m89/m120-verified): a-operand A[m=lane&15]
// [k=quad*8+j] -> m appears as D's ROW; b-operand B[n=lane&15][k] -> n is
// D's COL; C/D col=lane&15, row=quad*4+reg. Bias+ReLU in C-layout, masked
// for the ragged tail tile (1563*64=100032 > N_NODES), then shfl+LDS reduce
// -> per-block partials.
// ---------------------------------------------------------------------------
__global__ __launch_bounds__(256) void final_kernel(
    const float* __restrict__ feat, const float* __restrict__ acc,
    const float* __restrict__ W1, const float* __restrict__ b1,
    const float* __restrict__ W2, const float* __restrict__ b2,
    float* __restrict__ partials) {
    __shared__ short A_s[64 * ASTRIDE];  // [node][feat(0..63)|nbr(64..127)] bf16
    __shared__ short W_s[64 * ASTRIDE];  // [o][W1(0..63)|W2(64..127)] bf16
    __shared__ float red[4][64];

    const int tid  = threadIdx.x;
    const int lane = tid & 63;
    const int wave = tid >> 6;
    const int quad = lane >> 4;
    const int col  = lane & 15;
    const int node0 = blockIdx.x * 64;

    // Per-lane bias for output o = nb*16 + col (col == C/D column index).
    float bias[4];
#pragma unroll
    for (int nb = 0; nb < 4; ++nb) {
        const int o = nb * 16 + col;
        bias[nb] = b1[o] + b2[o];
    }

    // Stage W (bf16): 1024 float4 per matrix, 4 per thread, coalesced.
    {
        const float4* W1v = (const float4*)W1;
        const float4* W2v = (const float4*)W2;
#pragma unroll
        for (int i = 0; i < 4; ++i) {
            const int flat = tid + i * 256;   // 0..1023
            const int row = flat >> 4, c4 = flat & 15;
            *(s16x4*)&W_s[row * ASTRIDE + c4 * 4]      = f2bf4(W1v[flat]);
            *(s16x4*)&W_s[row * ASTRIDE + 64 + c4 * 4] = f2bf4(W2v[flat]);
        }
    }

    // Stage A tile (bf16): feat + nbr rows for nodes node0..node0+63.
    {
        const float4* fv = (const float4*)feat;
        const float4* av = (const float4*)acc;
#pragma unroll
        for (int i = 0; i < 4; ++i) {
            const int flat = tid + i * 256;
            const int row = flat >> 4, c4 = flat & 15;
            const int node = node0 + row;
            float4 f = make_float4(0.f, 0.f, 0.f, 0.f);
            float4 n = make_float4(0.f, 0.f, 0.f, 0.f);
            if (node < N_NODES) {
                f = fv[(size_t)node * 16 + c4];
                n = av[(size_t)node * 16 + c4];
            }
            *(s16x4*)&A_s[row * ASTRIDE + c4 * 4]      = f2bf4(f);
            *(s16x4*)&A_s[row * ASTRIDE + 64 + c4 * 4] = f2bf4(n);
        }
    }
    __syncthreads();

    // Hoist all 16 B-fragments (4 output-blocks x 4 k-steps) into VGPRs.
    bf16x8 Bf[4][4];
#pragma unroll
    for (int nb = 0; nb < 4; ++nb)
#pragma unroll
        for (int ks = 0; ks < 4; ++ks)
            Bf[nb][ks] = __builtin_bit_cast(bf16x8,
                *(const s16x8*)&W_s[(nb * 16 + col) * ASTRIDE + ks * 32 + quad * 8]);

    // This wave's 16-node strip x 64 outputs: 4 A reads + 16 MFMAs.
    f32x4 C[4];
#pragma unroll
    for (int nb = 0; nb < 4; ++nb) C[nb] = (f32x4){0.f, 0.f, 0.f, 0.f};
#pragma unroll
    for (int ks = 0; ks < 4; ++ks) {
        const bf16x8 Af = __builtin_bit_cast(bf16x8,
            *(const s16x8*)&A_s[(wave * 16 + col) * ASTRIDE + ks * 32 + quad * 8]);
#pragma unroll
        for (int nb = 0; nb < 4; ++nb)
            C[nb] = __builtin_amdgcn_mfma_f32_16x16x32_bf16(Af, Bf[nb][ks],
                                                            C[nb], 0, 0, 0);
    }

    // Epilogue: bias + ReLU per element (C-layout), mask OOB nodes, column
    // sums via shfl over quads, cross-wave combine in LDS.
    float sums[4] = {0.f, 0.f, 0.f, 0.f};
#pragma unroll
    for (int nb = 0; nb < 4; ++nb) {
#pragma unroll
        for (int reg = 0; reg < 4; ++reg) {
            const int node = node0 + wave * 16 + quad * 4 + reg;
            float u = C[nb][reg] + bias[nb];
            u = (u > 0.f) ? u : 0.f;
            if (node < N_NODES) sums[nb] += u;
        }
        sums[nb] += __shfl_xor(sums[nb], 16);
        sums[nb] += __shfl_xor(sums[nb], 32);
        if (lane < 16) red[wave][nb * 16 + lane] = sums[nb];
    }
    __syncthreads();
    if (tid < 64) {
        partials[blockIdx.x * 64 + tid] =
            red[0][tid] + red[1][tid] + red[2][tid] + red[3][tid];
    }
}

// ---------------------------------------------------------------------------
// Two-stage partials reduction (R9-proven; single-block version was 110us).
// ---------------------------------------------------------------------------
__global__ __launch_bounds__(256) void reduce1_kernel(
    const float* __restrict__ partials, float* __restrict__ part2) {
    __shared__ float red[4][64];
    const int col = threadIdx.x & 63;
    const int seg = threadIdx.x >> 6;
    const int r0 = blockIdx.x * R1_ROWS;
    int r1 = r0 + R1_ROWS;
    if (r1 > N_TILES) r1 = N_TILES;
    float s = 0.f;
    for (int r = r0 + seg; r < r1; r += 4) s += partials[r * 64 + col];
    red[seg][col] = s;
    __syncthreads();
    if (seg == 0) {
        part2[blockIdx.x * 64 + col] =
            red[0][col] + red[1][col] + red[2][col] + red[3][col];
    }
}

__global__ __launch_bounds__(256) void reduce2_kernel(
    const float* __restrict__ part2, float* __restrict__ out) {
    __shared__ float red[4][64];
    const int col = threadIdx.x & 63;
    const int seg = threadIdx.x >> 6;
    float s = 0.f;
    for (int r = seg; r < R1_BLOCKS; r += 4) s += part2[r * 64 + col];
    red[seg][col] = s;
    __syncthreads();
    if (seg == 0) {
        out[col] = red[0][col] + red[1][col] + red[2][col] + red[3][col];
    }
}

extern "C" void kernel_launch(void* const* d_in, const int* in_sizes, int n_in,
                              void* d_out, int out_size, void* d_ws, size_t ws_size,
                              hipStream_t stream) {
    const float* feat = (const float*)d_in[0];
    const float* emb  = (const float*)d_in[1];
    const float* W1   = (const float*)d_in[2];
    const float* b1   = (const float*)d_in[3];
    const float* W2   = (const float*)d_in[4];
    const float* b2   = (const float*)d_in[5];
    const int* edge_src = (const int*)d_in[6];
    const int* edge_dst = (const int*)d_in[7];
    float* out = (float*)d_out;
    char* ws = (char*)d_ws;

    if (ws_size >= (size_t)WS_NEEDED) {
        int*   cnt      = (int*)ws;
        int*   slots    = (int*)(ws + WS_SLOTS_OFF);
        float* acc      = (float*)(ws + WS_ACC_OFF);
        int*   ovf_cnt  = (int*)(ws + WS_OVFC_OFF);
        int2*  ovf      = (int2*)(ws + WS_OVF_OFF);
        float* partials = (float*)(ws + WS_PART_OFF);
        float* part2    = (float*)(ws + WS_PART2_OFF);

        (void)hipMemsetAsync(cnt, 0, N_NODES * sizeof(int), stream);
        (void)hipMemsetAsync(ovf_cnt, 0, sizeof(int), stream);

        fill_kernel<<<NR * N_SLICES, 256, 0, stream>>>(edge_src, edge_dst,
                                                       cnt, slots, ovf_cnt, ovf);
        gather_kernel<<<N_NODES / 4, 256, 0, stream>>>(emb, cnt, slots, acc);
        ovf_kernel<<<16, 256, 0, stream>>>(emb, ovf_cnt, ovf, acc);

        final_kernel<<<N_TILES, 256, 0, stream>>>(feat, acc, W1, b1, W2, b2,
                                                  partials);
        reduce1_kernel<<<R1_BLOCKS, 256, 0, stream>>>(partials, part2);
        reduce2_kernel<<<1, 256, 0, stream>>>(part2, out);
    } else {
        // Fallback: atomic scatter (correct but slow).
        float* acc = (float*)ws;
        (void)hipMemsetAsync(acc, 0, (size_t)N_NODES * D * sizeof(float), stream);
        scatter_kernel<<<(N_EDGES * 64) / 256, 256, 0, stream>>>(emb, edge_src,
                                                                 edge_dst, acc);
        float* partials = (float*)(ws + (size_t)N_NODES * D * sizeof(float));
        float* part2    = partials + (size_t)N_TILES * 64;
        final_kernel<<<N_TILES, 256, 0, stream>>>(feat, acc, W1, b1, W2, b2,
                                                  partials);
        reduce1_kernel<<<R1_BLOCKS, 256, 0, stream>>>(partials, part2);
        reduce2_kernel<<<1, 256, 0, stream>>>(part2, out);
    }
}